// Round 8
// baseline (891.016 us; speedup 1.0000x reference)
//
#include <hip/hip_runtime.h>
#include <hip/hip_bf16.h>

// ---------------------------------------------------------------------------
// Bidirectional GRU encoder (Keras reset_after=true), B=64 S=512 U=256 V=32000
// Round 8: round-4 structure (1024 thr, 4-way k-split, 96 U uints/thread)
//          + __launch_bounds__(1024, 1)  -> VGPR cap 128 (not 64), 1 wg/CU by
//          register-pool exhaustion (16 waves x 128 = 2048 = full pool).
//   k0a wt_prep : W fp32 -> Wtb [dir][768][256] bf16 (transposed)
//   k0b u_prep  : U fp32 -> per-thread fp16-pair blobs (384 B each)
//   k1  gx_mfma : gx = emb[x] @ W + b_in (+ b_rec for z,r), bf16 MFMA 16x16x32
//   k2  gru     : 128 wgs = (dir,batch) = 1 chain/CU, 1024 thr = 16 waves
//                 (4/SIMD). thread (j = t>>2, ks = t&3): k-slice 64,
//                 96 dot2/step, butterfly shfl_xor(1,2).
//                 h fp16 pairs in LDS: 4 regions of 32 ints, stride 40 ->
//                 wave's 4 b128 broadcast addrs hit disjoint bank quads.
//                 Double-buffered, 1 barrier/step, gx prefetch 1 step ahead.
// ws: [0,100663296) gx ; +786432 Wtb ; +786432 Upk   (~102.2 MB)
// ---------------------------------------------------------------------------

typedef _Float16 half2v __attribute__((ext_vector_type(2)));
typedef short short8 __attribute__((ext_vector_type(8)));
typedef float f32x4 __attribute__((ext_vector_type(4)));

__device__ __forceinline__ unsigned short f2bf(float f) {
  unsigned int u = __float_as_uint(f);
  return (unsigned short)((u + 0x7fffu + ((u >> 16) & 1u)) >> 16);  // RNE
}
__device__ __forceinline__ float bf2f(unsigned short v) {
  return __uint_as_float((unsigned int)v << 16);
}
__device__ __forceinline__ unsigned int packf16(float a, float b) {
  half2v v = {(_Float16)a, (_Float16)b};
  return __builtin_bit_cast(unsigned int, v);
}
__device__ __forceinline__ float dot2(unsigned int u, unsigned int hv, float acc) {
#if __has_builtin(__builtin_amdgcn_fdot2)
  return __builtin_amdgcn_fdot2(__builtin_bit_cast(half2v, u),
                                __builtin_bit_cast(half2v, hv), acc, false);
#else
  half2v a = __builtin_bit_cast(half2v, u), b = __builtin_bit_cast(half2v, hv);
  return acc + (float)a.x * (float)b.x + (float)a.y * (float)b.y;
#endif
}
__device__ __forceinline__ float sigf(float x) {
  return __builtin_amdgcn_rcpf(1.f + __expf(-x));
}
__device__ __forceinline__ float tanhfast(float x) {
  return 1.f - 2.f * __builtin_amdgcn_rcpf(1.f + __expf(2.f * x));
}

// ---------------- k0a: Wtb[dir][c][k] = bf16(W[k][c]) -----------------------
__global__ void __launch_bounds__(256) wt_prep_kernel(const float* __restrict__ Wf,
                                                      const float* __restrict__ Wb,
                                                      unsigned short* __restrict__ Wtb) {
  int o = blockIdx.x * 256 + threadIdx.x;
  if (o >= 2 * 768 * 256) return;
  int dir = o / (768 * 256);
  int rem = o % (768 * 256);
  int c = rem / 256, k = rem % 256;
  const float* W = dir ? Wb : Wf;
  Wtb[o] = f2bf(W[(size_t)k * 768 + c]);
}

// ---------------- k0b: per-thread U blobs (4-way k-split order) -------------
// id = dir*1024 + t, t = j*4 + ks. blob[96]: [uz 32 | ur 32 | uh 32];
// uz[p] = pack(U[ks*64+2p][j], U[ks*64+2p+1][j]); ur: col 256+j; uh: 512+j.
__global__ void __launch_bounds__(256) u_prep_kernel(const float* __restrict__ Uf,
                                                     const float* __restrict__ Ub,
                                                     unsigned int* __restrict__ Upk) {
  int id = blockIdx.x * 256 + threadIdx.x;   // 0..2047
  if (id >= 2048) return;
  int dir = id >> 10, t = id & 1023;
  int j = t >> 2, ks = t & 3;
  const float* U = dir ? Ub : Uf;
  unsigned int* o = Upk + (size_t)id * 96;
#pragma unroll
  for (int g = 0; g < 3; ++g) {
    int col = g * 256 + j;
#pragma unroll
    for (int p = 0; p < 32; ++p) {
      int k = ks * 64 + 2 * p;
      o[g * 32 + p] = packf16(U[(size_t)k * 768 + col], U[(size_t)(k + 1) * 768 + col]);
    }
  }
}

// ---------------- k1: gx = emb[x] @ W + bias, bf16 MFMA ---------------------
__global__ void __launch_bounds__(256) gx_mfma_kernel(
    const int* __restrict__ x, const float* __restrict__ emb,
    const unsigned short* __restrict__ Wtb,
    const float* __restrict__ bfv, const float* __restrict__ bbv,
    unsigned short* __restrict__ gx) {
  __shared__ __align__(16) unsigned short As[128 * 32];
  __shared__ __align__(16) unsigned short Bs[128 * 32];
  __shared__ int xid[128];

  int tid = threadIdx.x;
  int r0 = blockIdx.x * 128;
  int yt = blockIdx.y;
  int dir = (yt >= 6) ? 1 : 0;
  int c0 = (yt - dir * 6) * 128;
  const float* bv = dir ? bbv : bfv;
  const unsigned short* WtD = Wtb + (size_t)dir * 768 * 256;

  if (tid < 128) xid[tid] = x[r0 + tid];
  __syncthreads();

  int lane = tid & 63, w = tid >> 6;
  int wr = w >> 1, wc = w & 1;

  f32x4 acc[4][4] = {};

  for (int ks = 0; ks < 8; ++ks) {
#pragma unroll
    for (int i = 0; i < 2; ++i) {
      int s = tid + i * 256;
      int row = s >> 2, kslot = s & 3;
      int sw = kslot ^ ((row >> 2) & 3);
      const float* src = emb + (size_t)xid[row] * 256 + ks * 32 + kslot * 8;
      float4 f0 = *(const float4*)src;
      float4 f1 = *(const float4*)(src + 4);
      uint4 pa;
      pa.x = f2bf(f0.x) | ((unsigned)f2bf(f0.y) << 16);
      pa.y = f2bf(f0.z) | ((unsigned)f2bf(f0.w) << 16);
      pa.z = f2bf(f1.x) | ((unsigned)f2bf(f1.y) << 16);
      pa.w = f2bf(f1.z) | ((unsigned)f2bf(f1.w) << 16);
      *(uint4*)&As[row * 32 + sw * 8] = pa;
      uint4 pb = *(const uint4*)(WtD + (size_t)(c0 + row) * 256 + ks * 32 + kslot * 8);
      *(uint4*)&Bs[row * 32 + sw * 8] = pb;
    }
    __syncthreads();

    short8 a[4], b[4];
#pragma unroll
    for (int f = 0; f < 4; ++f) {
      int rowA = wr * 64 + f * 16 + (lane & 15);
      int swA = (lane >> 4) ^ ((rowA >> 2) & 3);
      a[f] = __builtin_bit_cast(short8, *(const uint4*)&As[rowA * 32 + swA * 8]);
      int rowB = wc * 64 + f * 16 + (lane & 15);
      int swB = (lane >> 4) ^ ((rowB >> 2) & 3);
      b[f] = __builtin_bit_cast(short8, *(const uint4*)&Bs[rowB * 32 + swB * 8]);
    }
#pragma unroll
    for (int fm = 0; fm < 4; ++fm)
#pragma unroll
      for (int fn = 0; fn < 4; ++fn)
        acc[fm][fn] = __builtin_amdgcn_mfma_f32_16x16x32_bf16(a[fm], b[fn], acc[fm][fn], 0, 0, 0);
    __syncthreads();
  }

#pragma unroll
  for (int fn = 0; fn < 4; ++fn) {
    int col = c0 + wc * 64 + fn * 16 + (lane & 15);
    float bias = bv[col] + (col < 512 ? bv[768 + col] : 0.f);
#pragma unroll
    for (int fm = 0; fm < 4; ++fm) {
      int rowb = r0 + wr * 64 + fm * 16 + (lane >> 4) * 4;
#pragma unroll
      for (int q = 0; q < 4; ++q) {
        gx[((size_t)dir * 32768 + rowb + q) * 768 + col] = f2bf(acc[fm][fn][q] + bias);
      }
    }
  }
}

// ---------------- k2: recurrence, 1024 thr, 4-way k-split, lb(1024,1) -------
__global__ void __launch_bounds__(1024, 1) gru_kernel(
    const unsigned int* __restrict__ Upk,    // [2*1024][96] fp16 pairs
    const unsigned short* __restrict__ gx,   // [2][32768][768] bf16
    const int* __restrict__ x,
    const float* __restrict__ bfv, const float* __restrict__ bbv,
    float* __restrict__ out) {
  int wg = blockIdx.x;
  int dir = wg >> 6, b = wg & 63;
  int t = threadIdx.x;
  int j = t >> 2;            // unit 0..255
  int ks = t & 3;            // k-quarter: k in [64ks, 64ks+64)

  // h fp16 pairs: 4 regions of 32 ints, stride 40 -> the wave's 4 broadcast
  // b128 addrs hit disjoint bank quads (0/8/16/24). Double-buffered.
  __shared__ unsigned int h_buf[2][160];

  const float brh = (dir ? bbv : bfv)[768 + 512 + j];
  const unsigned short* gxd = gx + ((size_t)dir * 32768 + (size_t)b * 512) * 768;
  const int* xb = x + b * 512;
  float* outb = out + ((size_t)b << 17);

  // one-time: 24 coalesced uint4 loads of this thread's U blob
  unsigned int uz[32], ur[32], uh[32];
  {
    const uint4* us = (const uint4*)(Upk + ((size_t)(dir << 10) + t) * 96);
#pragma unroll
    for (int q = 0; q < 8; ++q) {
      uint4 v = us[q];
      uz[4 * q] = v.x; uz[4 * q + 1] = v.y; uz[4 * q + 2] = v.z; uz[4 * q + 3] = v.w;
    }
#pragma unroll
    for (int q = 0; q < 8; ++q) {
      uint4 v = us[8 + q];
      ur[4 * q] = v.x; ur[4 * q + 1] = v.y; ur[4 * q + 2] = v.z; ur[4 * q + 3] = v.w;
    }
#pragma unroll
    for (int q = 0; q < 8; ++q) {
      uint4 v = us[16 + q];
      uh[4 * q] = v.x; uh[4 * q + 1] = v.y; uh[4 * q + 2] = v.z; uh[4 * q + 3] = v.w;
    }
  }
  if (t < 320) ((unsigned int*)h_buf)[t] = 0u;
  __syncthreads();

  // prologue: preload step 0's gx + mask
  int tt0 = dir ? 511 : 0;
  const unsigned short* g0 = gxd + (size_t)tt0 * 768;
  float gz = bf2f(g0[j]), gr = bf2f(g0[256 + j]), gh = bf2f(g0[512 + j]);
  int xv = xb[tt0];

  float hj = 0.f;
  int cur = 0;
  for (int step = 0; step < 512; ++step) {
    int tcur = dir ? (511 - step) : step;
    // prefetch next step (latency hidden under dot loop)
    float gz_n = 0.f, gr_n = 0.f, gh_n = 0.f;
    int xv_n = 0;
    if (step < 511) {
      int tn = dir ? (510 - step) : (step + 1);
      const unsigned short* gn = gxd + (size_t)tn * 768;
      gz_n = bf2f(gn[j]); gr_n = bf2f(gn[256 + j]); gh_n = bf2f(gn[512 + j]);
      xv_n = xb[tn];
    }

    float az0 = 0.f, az1 = 0.f, ar0 = 0.f, ar1 = 0.f, ah0 = 0.f, ah1 = 0.f;
    const unsigned int* hb = &h_buf[cur][ks * 40];
#pragma unroll
    for (int c = 0; c < 8; ++c) {
      uint4 hv = *(const uint4*)&hb[c * 4];   // 4 distinct addrs/wave, disjoint banks
      float& az = (c & 1) ? az1 : az0;
      float& ar = (c & 1) ? ar1 : ar0;
      float& ah = (c & 1) ? ah1 : ah0;
      az = dot2(uz[c * 4 + 0], hv.x, az);
      az = dot2(uz[c * 4 + 1], hv.y, az);
      az = dot2(uz[c * 4 + 2], hv.z, az);
      az = dot2(uz[c * 4 + 3], hv.w, az);
      ar = dot2(ur[c * 4 + 0], hv.x, ar);
      ar = dot2(ur[c * 4 + 1], hv.y, ar);
      ar = dot2(ur[c * 4 + 2], hv.z, ar);
      ar = dot2(ur[c * 4 + 3], hv.w, ar);
      ah = dot2(uh[c * 4 + 0], hv.x, ah);
      ah = dot2(uh[c * 4 + 1], hv.y, ah);
      ah = dot2(uh[c * 4 + 2], hv.z, ah);
      ah = dot2(uh[c * 4 + 3], hv.w, ah);
    }
    // butterfly over the 4 k-quarters (lanes t^1, t^2)
    float az = az0 + az1; az += __shfl_xor(az, 1); az += __shfl_xor(az, 2);
    float ar = ar0 + ar1; ar += __shfl_xor(ar, 1); ar += __shfl_xor(ar, 2);
    float ah = ah0 + ah1; ah += __shfl_xor(ah, 1); ah += __shfl_xor(ah, 2);

    float z = sigf(gz + az);
    float r = sigf(gr + ar);
    float hh = tanhfast(gh + r * (ah + brh));
    float hn = hh + z * (hj - hh);
    hn = (xv == 0) ? hj : hn;                  // masked: carry

    float hp = __shfl_xor(hn, 4);              // unit j^1's hn
    int m = t >> 3;                            // h-pair index 0..127
    if (((t & 4) == 0) && ((t & 3) == ((m >> 5) & 3))) {
      h_buf[cur ^ 1][(t & 3) * 40 + (m & 31)] = packf16(hn, hp);
    }
    __syncthreads();                           // one barrier per step

    if (ks == 0) atomicAdd(&outb[(size_t)tcur * 256 + j], hn);
    hj = hn; gz = gz_n; gr = gr_n; gh = gh_n; xv = xv_n;
    cur ^= 1;
  }
}

// ---------------------------------------------------------------------------
extern "C" void kernel_launch(void* const* d_in, const int* in_sizes, int n_in,
                              void* d_out, int out_size, void* d_ws, size_t ws_size,
                              hipStream_t stream) {
  const int*   x   = (const int*)d_in[0];
  const float* emb = (const float*)d_in[1];
  const float* Wf  = (const float*)d_in[2];
  const float* Uf  = (const float*)d_in[3];
  const float* bf_ = (const float*)d_in[4];
  const float* Wb  = (const float*)d_in[5];
  const float* Ub  = (const float*)d_in[6];
  const float* bb_ = (const float*)d_in[7];
  float* out = (float*)d_out;

  unsigned short* gxp = (unsigned short*)d_ws;                        // 100663296 B
  unsigned short* Wtb = (unsigned short*)((char*)d_ws + 100663296);   // 786432 B
  unsigned int*   Upk = (unsigned int*)((char*)d_ws + 100663296 + 786432);  // 786432 B

  hipMemsetAsync(d_out, 0, (size_t)out_size * sizeof(float), stream);

  wt_prep_kernel<<<1536, 256, 0, stream>>>(Wf, Wb, Wtb);
  u_prep_kernel<<<8, 256, 0, stream>>>(Uf, Ub, Upk);
  gx_mfma_kernel<<<dim3(256, 12), 256, 0, stream>>>(x, emb, Wtb, bf_, bb_, gxp);
  gru_kernel<<<128, 1024, 0, stream>>>(Upk, gxp, x, bf_, bb_, out);
}